// Round 3
// baseline (1011.445 us; speedup 1.0000x reference)
//
#include <hip/hip_runtime.h>
#include <hip/hip_bf16.h>
#include <hip/hip_fp16.h>

// Problem constants
#define NB 8
#define NT 1024
#define MD 1024
#define SD 256
#define NSTATES 16
#define NTOK (NB*NT)            // 8192
#define OUT_MAIN (NTOK*MD)      // 8388608

typedef __attribute__((ext_vector_type(8))) short bf16x8;
typedef __attribute__((ext_vector_type(4))) float f32x4;
typedef _Float16 f16x2 __attribute__((ext_vector_type(2)));

#if defined(__has_builtin)
#if __has_builtin(__builtin_amdgcn_fdot2)
#define HAVE_FDOT2 1
#endif
#endif

static __device__ __forceinline__ unsigned short f32_to_bf16_bits(float f) {
    union { float f; unsigned u; } v; v.f = f;
    unsigned r = v.u + 0x7FFFu + ((v.u >> 16) & 1u);
    return (unsigned short)(r >> 16);
}

static __device__ __forceinline__ float fdot2f(unsigned hbits, unsigned wbits, float acc) {
#ifdef HAVE_FDOT2
    return __builtin_amdgcn_fdot2(__builtin_bit_cast(f16x2, hbits),
                                  __builtin_bit_cast(f16x2, wbits), acc, false);
#else
    f16x2 hv = __builtin_bit_cast(f16x2, hbits), wv = __builtin_bit_cast(f16x2, wbits);
    return acc + (float)hv.x * (float)wv.x + (float)hv.y * (float)wv.y;
#endif
}

static __device__ __forceinline__ float fast_exp2(float x) {
#if __has_builtin(__builtin_amdgcn_exp2f)
    return __builtin_amdgcn_exp2f(x);
#else
    return exp2f(x);
#endif
}
static __device__ __forceinline__ float fast_rcp(float x) {
#if __has_builtin(__builtin_amdgcn_rcpf)
    return __builtin_amdgcn_rcpf(x);
#else
    return 1.f / x;
#endif
}

// quad butterfly sum over lanes {l, l^1, l^2, l^3} — VALU pipe (DPP), no DS ops
static __device__ __forceinline__ float qsum(float v) {
    int x = __builtin_bit_cast(int, v);
    int y = __builtin_amdgcn_update_dpp(0, x, 0xB1, 0xF, 0xF, true);  // quad_perm [1,0,3,2]
    v += __builtin_bit_cast(float, y);
    x = __builtin_bit_cast(int, v);
    y = __builtin_amdgcn_update_dpp(0, x, 0x4E, 0xF, 0xF, true);      // quad_perm [2,3,0,1]
    v += __builtin_bit_cast(float, y);
    return v;
}

// async global(16B/lane) -> LDS (wave-uniform base, lane*16 stride)
static __device__ __forceinline__ void gld16(const void* g, void* l) {
    __builtin_amdgcn_global_load_lds(
        (const __attribute__((address_space(1))) void*)g,
        (__attribute__((address_space(3))) void*)l, 16, 0, 0);
}

#define STEP_BARRIER() do { \
    asm volatile("s_waitcnt lgkmcnt(0)" ::: "memory"); \
    __builtin_amdgcn_s_barrier(); \
    asm volatile("" ::: "memory"); } while (0)

// ---------------------------------------------------------------------------
// K1: out = base (exact f32 copy), zero accumulators (ent_sum f32, count u32)
__global__ void k_copy_zero(const float4* __restrict__ base, float4* __restrict__ out,
                            float* __restrict__ accums) {
    unsigned i = blockIdx.x * 256u + threadIdx.x;
    const unsigned STRIDE = 524288u; // total float4 = 2097152
#pragma unroll
    for (int q = 0; q < 4; q++) out[i + q * STRIDE] = base[i + q * STRIDE];
    if (i == 0u) { accums[0] = 0.f; ((unsigned*)accums)[1] = 0u; }
}

// ---------------------------------------------------------------------------
// K2: prep weights + active list.
//  - Bt[512][1024] bf16 : row n = column n of [Wsi|Wgi]
//  - Wpack: per-thread recurrent weights for k_rec, f16x2 packed, laid out so
//    thread tid reads uint4 wr4[i4] = Wpack4[i4*512+tid], i4 = (jj*2+o)*8+q,
//    component p: pack of W_o[k..k+1][j], k = kq*64 + ((q^kq)&7)*8 + 2p,
//    j = jj*128 + wv*16 + jl  (kq=tid&3, jl=(tid>>2)&15, wv=tid>>6)
//  - active list: (tok<<6)|slot appended with atomic counter
__global__ void k_prep(const float* __restrict__ Wsi, const float* __restrict__ Wgi,
                       const float* __restrict__ Wsh, const float* __restrict__ Wgh,
                       const int* __restrict__ ids, const int* __restrict__ t2s,
                       unsigned short* __restrict__ Bt, unsigned* __restrict__ Wpack,
                       unsigned* __restrict__ list, unsigned* __restrict__ countp) {
    unsigned i = blockIdx.x * 256u + threadIdx.x;
    if (i < 524288u) {
        unsigned n = i >> 10, k = i & 1023u;
        float v = (n < 256u) ? Wsi[k * 256u + n] : Wgi[k * 256u + (n - 256u)];
        Bt[i] = f32_to_bf16_bits(v);
    } else if (i < 589824u) {
        unsigned w = i - 524288u;            // 0..65535
        unsigned e   = w & 3u;               // p = uint4 component
        unsigned tid = (w >> 2) & 511u;
        unsigned i4  = w >> 11;              // 0..31
        unsigned q   = i4 & 7u;
        unsigned o   = (i4 >> 3) & 1u;
        unsigned jj  = i4 >> 4;
        unsigned kq  = tid & 3u;
        unsigned jl  = (tid >> 2) & 15u;
        unsigned wv  = tid >> 6;
        unsigned j   = jj * 128u + wv * 16u + jl;
        unsigned k   = kq * 64u + ((q ^ kq) & 7u) * 8u + 2u * e;
        const float* W = o ? Wgh : Wsh;
        union { _Float16 h[2]; unsigned u; } pk;
        pk.h[0] = (_Float16)W[k * 256u + j];
        pk.h[1] = (_Float16)W[(k + 1u) * 256u + j];
        Wpack[w] = pk.u;
    } else if (i < 598016u) {
        unsigned tok = i - 589824u;
        int slot = t2s[ids[tok]];
        if (slot >= 0) {
            unsigned pos = atomicAdd(countp, 1u);
            list[pos] = (tok << 6) | (unsigned)slot;
        }
    }
}

// ---------------------------------------------------------------------------
// K3: XW[8192][512] f32 = bf16(base) @ [Wsi|Wgi]  (unchanged)
__launch_bounds__(512, 1)
__global__ void k_gemm(const float* __restrict__ A, const unsigned short* __restrict__ Bt,
                       float* __restrict__ XW) {
    __shared__ __align__(16) unsigned short Abuf[128 * 40];
    __shared__ __align__(16) unsigned short Bbuf[256 * 40];
    const unsigned tid = threadIdx.x;
    const unsigned m0 = blockIdx.x * 128u;
    const unsigned n0 = blockIdx.y * 256u;
    const unsigned wave = tid >> 6, lane = tid & 63u;
    const unsigned wm = wave >> 2, wn = wave & 3u;
    const unsigned l15 = lane & 15u, kg = lane >> 4;
    const unsigned ar = tid >> 2;
    const unsigned ac = (tid & 3u) * 8u;

    f32x4 acc[4][4];
#pragma unroll
    for (int i = 0; i < 4; i++)
#pragma unroll
        for (int j = 0; j < 4; j++) acc[i][j] = (f32x4){0.f, 0.f, 0.f, 0.f};

    for (unsigned k0 = 0; k0 < 1024u; k0 += 32u) {
        {
            const float* src = A + (size_t)(m0 + ar) * 1024u + k0 + ac;
            float4 f0 = *(const float4*)src;
            float4 f1 = *(const float4*)(src + 4);
            unsigned short* dst = &Abuf[ar * 40u + ac];
            dst[0] = f32_to_bf16_bits(f0.x); dst[1] = f32_to_bf16_bits(f0.y);
            dst[2] = f32_to_bf16_bits(f0.z); dst[3] = f32_to_bf16_bits(f0.w);
            dst[4] = f32_to_bf16_bits(f1.x); dst[5] = f32_to_bf16_bits(f1.y);
            dst[6] = f32_to_bf16_bits(f1.z); dst[7] = f32_to_bf16_bits(f1.w);
        }
#pragma unroll
        for (int q = 0; q < 2; q++) {
            unsigned br = q * 128u + (tid >> 2);
            const unsigned short* src = Bt + (size_t)(n0 + br) * 1024u + k0 + ac;
            *(uint4*)&Bbuf[br * 40u + ac] = *(const uint4*)src;
        }
        __syncthreads();
        bf16x8 a[4], b[4];
#pragma unroll
        for (int i = 0; i < 4; i++)
            a[i] = *(const bf16x8*)&Abuf[(wm * 64u + i * 16u + l15) * 40u + kg * 8u];
#pragma unroll
        for (int j = 0; j < 4; j++)
            b[j] = *(const bf16x8*)&Bbuf[(wn * 64u + j * 16u + l15) * 40u + kg * 8u];
#pragma unroll
        for (int i = 0; i < 4; i++)
#pragma unroll
            for (int j = 0; j < 4; j++)
                acc[i][j] = __builtin_amdgcn_mfma_f32_16x16x32_bf16(a[i], b[j], acc[i][j], 0, 0, 0);
        __syncthreads();
    }
#pragma unroll
    for (int i = 0; i < 4; i++) {
        unsigned row_b = m0 + wm * 64u + i * 16u + kg * 4u;
#pragma unroll
        for (int j = 0; j < 4; j++) {
            unsigned col = n0 + wn * 64u + j * 16u + l15;
#pragma unroll
            for (int r = 0; r < 4; r++)
                XW[(size_t)(row_b + r) * 512u + col] = acc[i][j][r];
        }
    }
}

// ---------------------------------------------------------------------------
// K4: sequential GRU recurrence, v3.
// One WG per batch, 512 threads (8 waves). Lane quad (kq = lane&3) splits K
// into quarters; quad owns outputs j1 = wv*16+jl (s,g) and j2 = 128+wv*16+jl.
// Cross-kq reduce via DPP quad-perm adds (VALU pipe, no DS). h double-buffered
// f16 in LDS, XOR-swizzled read order (chunk = q^kq) -> conflict-free, with
// weights pre-permuted to match. XW staged in 8-step LDS chunks via
// global_load_lds with counted vmcnt(8) waits (prefix stores never drained).
__launch_bounds__(512, 2)
__global__ void k_rec(const float* __restrict__ XW, const unsigned* __restrict__ Wpack,
                      float* __restrict__ prefix) {
    __shared__ __align__(16) unsigned short hH[2][256];
    __shared__ __align__(16) float xwC[2][8 * 512];
    const unsigned tid = threadIdx.x;
    const unsigned lane = tid & 63u, wv = tid >> 6;
    const unsigned kq = lane & 3u, jl = lane >> 2;
    const unsigned j1 = wv * 16u + jl;
    const unsigned j2 = 128u + wv * 16u + jl;
    const unsigned jsel = (kq & 1u) ? j2 : j1;
    const unsigned b = blockIdx.x;

    // register-resident weights: 32 uint4 = 128 packed f16x2
    uint4 wr4[32];
#pragma unroll
    for (int i4 = 0; i4 < 32; i4++) wr4[i4] = ((const uint4*)Wpack)[i4 * 512 + tid];

    if (tid < 32u) ((uint4*)&hH[0][0])[tid] = (uint4){0u, 0u, 0u, 0u};

    const float* xwb = XW + (size_t)b * (1024u * 512u);
    float* pfb = prefix + (size_t)b * (1024u * 256u);

    // issue chunk c (8 steps = 4096 floats) into xwC[c&1]; 8 waves x 512 floats
    auto issue = [&](unsigned c) {
        const float* src = xwb + (size_t)c * 4096u;
        float* dst = &xwC[c & 1u][0];
#pragma unroll
        for (int qq = 0; qq < 2; qq++) {
            unsigned off = (wv * 2u + (unsigned)qq) * 256u;   // wave-uniform
            gld16(src + off + lane * 4u, dst + off);
        }
    };
    issue(0u);

    const float L2E = 1.4426950408889634f;
    float hold = 0.f;
    unsigned t = 0;
    for (unsigned c = 0; c < 128u; ++c) {
        if (c == 0u) { asm volatile("s_waitcnt vmcnt(0) lgkmcnt(0)" ::: "memory"); }
        else         { asm volatile("s_waitcnt vmcnt(8) lgkmcnt(0)" ::: "memory"); }
        __builtin_amdgcn_s_barrier();
        asm volatile("" ::: "memory");
        if (c + 1u < 128u) issue(c + 1u);
        const float* xc = &xwC[c & 1u][0];
        for (unsigned s = 0; s < 8u; ++s, ++t) {
            const char* hb = (const char*)&hH[0][0] + ((t & 1u) << 9) + (kq << 7);
            float a00 = 0.f, a01 = 0.f, a10 = 0.f, a11 = 0.f;
#pragma unroll
            for (unsigned q = 0; q < 8u; q++) {
                uint4 h4 = *(const uint4*)(hb + ((q ^ kq) & 7u) * 16u);
                uint4 w00 = wr4[q], w01 = wr4[8 + q], w10 = wr4[16 + q], w11 = wr4[24 + q];
                a00 = fdot2f(h4.x, w00.x, a00); a01 = fdot2f(h4.x, w01.x, a01);
                a10 = fdot2f(h4.x, w10.x, a10); a11 = fdot2f(h4.x, w11.x, a11);
                a00 = fdot2f(h4.y, w00.y, a00); a01 = fdot2f(h4.y, w01.y, a01);
                a10 = fdot2f(h4.y, w10.y, a10); a11 = fdot2f(h4.y, w11.y, a11);
                a00 = fdot2f(h4.z, w00.z, a00); a01 = fdot2f(h4.z, w01.z, a01);
                a10 = fdot2f(h4.z, w10.z, a10); a11 = fdot2f(h4.z, w11.z, a11);
                a00 = fdot2f(h4.w, w00.w, a00); a01 = fdot2f(h4.w, w01.w, a01);
                a10 = fdot2f(h4.w, w10.w, a10); a11 = fdot2f(h4.w, w11.w, a11);
            }
            float s1 = qsum(a00), g1 = qsum(a01), s2 = qsum(a10), g2 = qsum(a11);
            float s_sel = (kq & 1u) ? s2 : s1;
            float g_sel = (kq & 1u) ? g2 : g1;
            s_sel += xc[s * 512u + jsel];
            g_sel += xc[s * 512u + 256u + jsel];
            float gate = fast_rcp(1.f + fast_exp2(-g_sel * L2E));
            float prop = 1.f - 2.f * fast_rcp(1.f + fast_exp2(2.f * L2E * s_sel));
            float hnew = hold + gate * (prop - hold);
            if (kq < 2u) {
                pfb[t * 256u + jsel] = hold;               // fire-and-forget
                union { _Float16 h; unsigned short u; } cv; cv.h = (_Float16)hnew;
                hH[(t + 1u) & 1u][jsel] = cv.u;
            }
            hold = hnew;
            if (s < 7u) STEP_BARRIER();
        }
    }
}

// ---------------------------------------------------------------------------
// K5: router + delta mix at active tokens only. grid-stride over device count.
__launch_bounds__(256, 1)
__global__ void k_router(const unsigned* __restrict__ list, const float* __restrict__ accums_ro,
                         const float* __restrict__ prefix, const float* __restrict__ base,
                         const float* __restrict__ Wrh, const float* __restrict__ Wro,
                         const float* __restrict__ delta, float* __restrict__ out,
                         float* __restrict__ ent_sum) {
    const unsigned cnt = ((const unsigned*)accums_ro)[1];
    __shared__ float f[1280];
    __shared__ float hid[256];
    __shared__ float pr[16];
    const unsigned tid = threadIdx.x;
    for (unsigned idx = blockIdx.x; idx < cnt; idx += gridDim.x) {
        unsigned e = list[idx];
        unsigned tok = e >> 6, slot = e & 63u;
        f[tid] = prefix[(size_t)tok * 256u + tid];
#pragma unroll
        for (int q = 0; q < 4; q++)
            f[256u + q * 256u + tid] = base[(size_t)tok * 1024u + q * 256u + tid];
        __syncthreads();
        float a = 0.f;
        for (unsigned k = 0; k < 1280u; k++) a += f[k] * Wrh[k * 256u + tid];
        hid[tid] = tanhf(a);
        __syncthreads();
        if (tid < 16u) {
            float l = 0.f;
            for (unsigned k = 0; k < 256u; k++) l += hid[k] * Wro[k * 16u + tid];
            pr[tid] = l;
        }
        __syncthreads();
        if (tid == 0u) {
            float m = pr[0];
#pragma unroll
            for (int n = 1; n < 16; n++) m = fmaxf(m, pr[n]);
            float es[16]; float ssum = 0.f;
#pragma unroll
            for (int n = 0; n < 16; n++) { es[n] = expf(pr[n] - m); ssum += es[n]; }
            float inv = 1.f / ssum, ent = 0.f;
#pragma unroll
            for (int n = 0; n < 16; n++) {
                float p = es[n] * inv;
                pr[n] = p;
                ent -= p * logf(fmaxf(p, 1e-8f));
            }
            atomicAdd(ent_sum, ent);
        }
        __syncthreads();
        {
            const float* dslot = delta + (size_t)slot * 16u * 1024u;
            unsigned d0 = tid * 4u;
            float4 m4 = {0.f, 0.f, 0.f, 0.f};
#pragma unroll
            for (int n = 0; n < 16; n++) {
                float p = pr[n];
                float4 dv = *(const float4*)(dslot + n * 1024u + d0);
                m4.x += p * dv.x; m4.y += p * dv.y; m4.z += p * dv.z; m4.w += p * dv.w;
            }
            float* op = out + (size_t)tok * 1024u + d0;
            float4 cur = *(const float4*)op;
            cur.x += 0.25f * m4.x; cur.y += 0.25f * m4.y;
            cur.z += 0.25f * m4.z; cur.w += 0.25f * m4.w;
            *(float4*)op = cur;
        }
        __syncthreads();
    }
}

// ---------------------------------------------------------------------------
// K6: scalars
__global__ void k_final(const float* __restrict__ accums, float* __restrict__ out) {
    float ent = accums[0];
    unsigned cnt = ((const unsigned*)accums)[1];
    out[OUT_MAIN]     = (cnt > 0u) ? ent / (float)cnt : 0.f;
    out[OUT_MAIN + 1] = (float)cnt / 8192.f;
}

// ---------------------------------------------------------------------------
extern "C" void kernel_launch(void* const* d_in, const int* in_sizes, int n_in,
                              void* d_out, int out_size, void* d_ws, size_t ws_size,
                              hipStream_t stream) {
    const int*   ids  = (const int*)d_in[0];
    const float* base = (const float*)d_in[1];
    const int*   t2s  = (const int*)d_in[2];
    const float* Wsi  = (const float*)d_in[3];
    const float* Wsh  = (const float*)d_in[4];
    const float* Wgi  = (const float*)d_in[5];
    const float* Wgh  = (const float*)d_in[6];
    const float* Wrh  = (const float*)d_in[7];
    const float* Wro  = (const float*)d_in[8];
    const float* delta = (const float*)d_in[9];
    float* out = (float*)d_out;

    char* ws = (char*)d_ws;
    float*          XW     = (float*)(ws);                      // 16,777,216 B
    float*          prefix = (float*)(ws + 16777216);           //  8,388,608 B
    unsigned short* Bt     = (unsigned short*)(ws + 25165824);  //  1,048,576 B
    unsigned*       Wpack  = (unsigned*)(ws + 26214400);        //    262,144 B
    unsigned*       list   = (unsigned*)(ws + 26476544);        //     32,768 B
    float*          accums = (float*)(ws + 26509312);           //          8 B

    hipLaunchKernelGGL(k_copy_zero, dim3(2048), dim3(256), 0, stream,
                       (const float4*)base, (float4*)out, accums);
    hipLaunchKernelGGL(k_prep, dim3(2336), dim3(256), 0, stream,
                       Wsi, Wgi, Wsh, Wgh, ids, t2s, Bt, Wpack, list,
                       (unsigned*)accums + 1);
    hipLaunchKernelGGL(k_gemm, dim3(64, 2), dim3(512), 0, stream, base, Bt, XW);
    hipLaunchKernelGGL(k_rec, dim3(8), dim3(512), 0, stream, XW, Wpack, prefix);
    hipLaunchKernelGGL(k_router, dim3(64), dim3(256), 0, stream,
                       list, accums, prefix, base, Wrh, Wro, delta, out, accums);
    hipLaunchKernelGGL(k_final, dim3(1), dim3(1), 0, stream, accums, out);
}

// Round 4
// 707.394 us; speedup vs baseline: 1.4298x; 1.4298x over previous
//
#include <hip/hip_runtime.h>
#include <hip/hip_bf16.h>
#include <hip/hip_fp16.h>

// Problem constants
#define NB 8
#define NT 1024
#define MD 1024
#define SD 256
#define NSTATES 16
#define NTOK (NB*NT)            // 8192
#define OUT_MAIN (NTOK*MD)      // 8388608

typedef __attribute__((ext_vector_type(8))) short bf16x8;
typedef __attribute__((ext_vector_type(4))) float f32x4;

static __device__ __forceinline__ unsigned short f32_to_bf16_bits(float f) {
    union { float f; unsigned u; } v; v.f = f;
    unsigned r = v.u + 0x7FFFu + ((v.u >> 16) & 1u);
    return (unsigned short)(r >> 16);
}

#if defined(__has_builtin)
#if __has_builtin(__builtin_amdgcn_sdot4)
#define DOT4(acc, h, w) acc = __builtin_amdgcn_sdot4((int)(h), (int)(w), acc, false)
#endif
#endif
#ifndef DOT4
#define DOT4(acc, h, w) asm("v_dot4_i32_i8 %0, %1, %2, %0" : "+v"(acc) : "v"(h), "v"(w))
#endif

static __device__ __forceinline__ float fast_exp2(float x) {
#if __has_builtin(__builtin_amdgcn_exp2f)
    return __builtin_amdgcn_exp2f(x);
#else
    return exp2f(x);
#endif
}
static __device__ __forceinline__ float fast_rcp(float x) {
#if __has_builtin(__builtin_amdgcn_rcpf)
    return __builtin_amdgcn_rcpf(x);
#else
    return 1.f / x;
#endif
}

// int butterfly-add over 8 consecutive lanes: xor1, xor2, mirror-within-8 (==xor7)
static __device__ __forceinline__ int bsum8(int v) {
    v += __builtin_amdgcn_update_dpp(0, v, 0xB1,  0xF, 0xF, true);  // quad_perm [1,0,3,2]
    v += __builtin_amdgcn_update_dpp(0, v, 0x4E,  0xF, 0xF, true);  // quad_perm [2,3,0,1]
    v += __builtin_amdgcn_update_dpp(0, v, 0x141, 0xF, 0xF, true);  // row_half_mirror
    return v;
}

// async global(16B/lane) -> LDS (wave-uniform base, lane*16 stride)
static __device__ __forceinline__ void gld16(const void* g, void* l) {
    __builtin_amdgcn_global_load_lds(
        (const __attribute__((address_space(1))) void*)g,
        (__attribute__((address_space(3))) void*)l, 16, 0, 0);
}

#define STEP_BARRIER() do { \
    asm volatile("s_waitcnt lgkmcnt(0)" ::: "memory"); \
    __builtin_amdgcn_s_barrier(); \
    asm volatile("" ::: "memory"); } while (0)

// ---------------------------------------------------------------------------
// K1: out = base (exact f32 copy), zero accumulators (ent_sum f32, count u32)
__global__ void k_copy_zero(const float4* __restrict__ base, float4* __restrict__ out,
                            float* __restrict__ accums) {
    unsigned i = blockIdx.x * 256u + threadIdx.x;
    const unsigned STRIDE = 524288u; // total float4 = 2097152
#pragma unroll
    for (int q = 0; q < 4; q++) out[i + q * STRIDE] = base[i + q * STRIDE];
    if (i == 0u) { accums[0] = 0.f; ((unsigned*)accums)[1] = 0u; }
}

// ---------------------------------------------------------------------------
// K2: prep weights + active list.
//  - Bt[512][1024] bf16 : row n = column n of [Wsi|Wgi]
//  - Wpack: int8-quantized recurrent weights (scale 1270), packed per-thread:
//    uint index w = 4*(i4*512+tid)+e, i4 = a*2+q (a=0..7 acc, q=0..1 read instr)
//    thread decomp: lane=tid&63, wv=tid>>6, ko=lane&7, jg=lane>>3, G=wv*8+jg,
//    j = 4G+(a&3), o=a>>2 (0:Wsh,1:Wgh), c=(q^(ko&1))&1, k0=ko*32+c*16+e*4,
//    uint packs W_o[k0+r][j], r=0..3 as i8 bytes (little-endian)
//  - active list: (tok<<6)|slot appended with atomic counter
__global__ void k_prep(const float* __restrict__ Wsi, const float* __restrict__ Wgi,
                       const float* __restrict__ Wsh, const float* __restrict__ Wgh,
                       const int* __restrict__ ids, const int* __restrict__ t2s,
                       unsigned short* __restrict__ Bt, unsigned* __restrict__ Wpack,
                       unsigned* __restrict__ list, unsigned* __restrict__ countp) {
    unsigned i = blockIdx.x * 256u + threadIdx.x;
    if (i < 524288u) {
        unsigned n = i >> 10, k = i & 1023u;
        float v = (n < 256u) ? Wsi[k * 256u + n] : Wgi[k * 256u + (n - 256u)];
        Bt[i] = f32_to_bf16_bits(v);
    } else if (i < 557056u) {
        unsigned w = i - 524288u;            // 0..32767
        unsigned e   = w & 3u;
        unsigned tid = (w >> 2) & 511u;
        unsigned i4  = w >> 11;              // 0..15
        unsigned q   = i4 & 1u;
        unsigned a   = i4 >> 1;              // 0..7
        unsigned lane = tid & 63u, wv = tid >> 6;
        unsigned ko = lane & 7u, jg = lane >> 3;
        unsigned G  = wv * 8u + jg;
        unsigned j  = 4u * G + (a & 3u);
        unsigned c  = (q ^ (ko & 1u)) & 1u;
        unsigned k0 = ko * 32u + c * 16u + e * 4u;
        const float* W = (a >> 2) ? Wgh : Wsh;
        unsigned word = 0u;
#pragma unroll
        for (int r = 0; r < 4; r++) {
            float wf = W[(k0 + (unsigned)r) * 256u + j];
            int iv = (int)rintf(wf * 1270.f);
            iv = iv > 127 ? 127 : (iv < -127 ? -127 : iv);
            word |= ((unsigned)iv & 0xFFu) << (8 * r);
        }
        Wpack[w] = word;
    } else if (i < 565248u) {
        unsigned tok = i - 557056u;
        int slot = t2s[ids[tok]];
        if (slot >= 0) {
            unsigned pos = atomicAdd(countp, 1u);
            list[pos] = (tok << 6) | (unsigned)slot;
        }
    }
}

// ---------------------------------------------------------------------------
// K3: XW[8192][512] f32 = bf16(base) @ [Wsi|Wgi]  (unchanged)
__launch_bounds__(512, 1)
__global__ void k_gemm(const float* __restrict__ A, const unsigned short* __restrict__ Bt,
                       float* __restrict__ XW) {
    __shared__ __align__(16) unsigned short Abuf[128 * 40];
    __shared__ __align__(16) unsigned short Bbuf[256 * 40];
    const unsigned tid = threadIdx.x;
    const unsigned m0 = blockIdx.x * 128u;
    const unsigned n0 = blockIdx.y * 256u;
    const unsigned wave = tid >> 6, lane = tid & 63u;
    const unsigned wm = wave >> 2, wn = wave & 3u;
    const unsigned l15 = lane & 15u, kg = lane >> 4;
    const unsigned ar = tid >> 2;
    const unsigned ac = (tid & 3u) * 8u;

    f32x4 acc[4][4];
#pragma unroll
    for (int i = 0; i < 4; i++)
#pragma unroll
        for (int j = 0; j < 4; j++) acc[i][j] = (f32x4){0.f, 0.f, 0.f, 0.f};

    for (unsigned k0 = 0; k0 < 1024u; k0 += 32u) {
        {
            const float* src = A + (size_t)(m0 + ar) * 1024u + k0 + ac;
            float4 f0 = *(const float4*)src;
            float4 f1 = *(const float4*)(src + 4);
            unsigned short* dst = &Abuf[ar * 40u + ac];
            dst[0] = f32_to_bf16_bits(f0.x); dst[1] = f32_to_bf16_bits(f0.y);
            dst[2] = f32_to_bf16_bits(f0.z); dst[3] = f32_to_bf16_bits(f0.w);
            dst[4] = f32_to_bf16_bits(f1.x); dst[5] = f32_to_bf16_bits(f1.y);
            dst[6] = f32_to_bf16_bits(f1.z); dst[7] = f32_to_bf16_bits(f1.w);
        }
#pragma unroll
        for (int q = 0; q < 2; q++) {
            unsigned br = q * 128u + (tid >> 2);
            const unsigned short* src = Bt + (size_t)(n0 + br) * 1024u + k0 + ac;
            *(uint4*)&Bbuf[br * 40u + ac] = *(const uint4*)src;
        }
        __syncthreads();
        bf16x8 a[4], b[4];
#pragma unroll
        for (int i = 0; i < 4; i++)
            a[i] = *(const bf16x8*)&Abuf[(wm * 64u + i * 16u + l15) * 40u + kg * 8u];
#pragma unroll
        for (int j = 0; j < 4; j++)
            b[j] = *(const bf16x8*)&Bbuf[(wn * 64u + j * 16u + l15) * 40u + kg * 8u];
#pragma unroll
        for (int i = 0; i < 4; i++)
#pragma unroll
            for (int j = 0; j < 4; j++)
                acc[i][j] = __builtin_amdgcn_mfma_f32_16x16x32_bf16(a[i], b[j], acc[i][j], 0, 0, 0);
        __syncthreads();
    }
#pragma unroll
    for (int i = 0; i < 4; i++) {
        unsigned row_b = m0 + wm * 64u + i * 16u + kg * 4u;
#pragma unroll
        for (int j = 0; j < 4; j++) {
            unsigned col = n0 + wn * 64u + j * 16u + l15;
#pragma unroll
            for (int r = 0; r < 4; r++)
                XW[(size_t)(row_b + r) * 512u + col] = acc[i][j][r];
        }
    }
}

// ---------------------------------------------------------------------------
// K4: sequential GRU recurrence, v4 (int8 dot4).
// One WG per batch, 512 threads (8 waves). Lane octet (ko = lane&7) splits K
// into eighths; group (wv, jg=lane>>3) owns columns 4G..4G+3 for both s and g.
// h stored as i8[256] double-buffered in LDS (scale 127); weights i8 in 64
// VGPRs (scale 1270); v_dot4_i32_i8 MACs; DPP butterfly reduce (VALU pipe).
// One barrier/step; xw staged in 8-step LDS chunks via global_load_lds with
// counted vmcnt(8) (prefix stores never drained).
__launch_bounds__(512, 2)
__global__ void k_rec(const float* __restrict__ XW, const unsigned* __restrict__ Wpack,
                      float* __restrict__ prefix) {
    __shared__ __align__(16) unsigned char hB[2][256];
    __shared__ __align__(16) float xwC[2][8 * 512];
    const unsigned tid = threadIdx.x;
    const unsigned lane = tid & 63u, wv = tid >> 6;
    const unsigned ko = lane & 7u, jg = lane >> 3;
    const unsigned G = wv * 8u + jg;
    const unsigned jc = ko & 3u;
    const unsigned j = 4u * G + jc;
    const unsigned b = blockIdx.x;

    // register-resident weights: 16 uint4 = 64 VGPRs of packed i8
    uint4 w[8][2];
#pragma unroll
    for (int a = 0; a < 8; a++)
#pragma unroll
        for (int q = 0; q < 2; q++)
            w[a][q] = ((const uint4*)Wpack)[(a * 2 + q) * 512 + tid];

    if (tid < 128u) ((unsigned*)&hB[0][0])[tid] = 0u;   // zero both h buffers

    // per-lane h read offsets (XOR order across the octet -> 2-way only)
    const unsigned c0 = ko & 1u;
    const unsigned off_q0 = ko * 32u + c0 * 16u;
    const unsigned off_q1 = ko * 32u + (c0 ^ 1u) * 16u;
    const unsigned char* hbp0 = &hB[0][0];
    const unsigned char* hbp1 = &hB[1][0];

    const float* xwb = XW + (size_t)b * (1024u * 512u);
    float* pfb = prefix + (size_t)b * (1024u * 256u) + j;

    auto issue = [&](unsigned c) {
        const float* src = xwb + (size_t)c * 4096u;
        float* dst = &xwC[c & 1u][0];
#pragma unroll
        for (int qq = 0; qq < 2; qq++) {
            unsigned off = (wv * 2u + (unsigned)qq) * 256u;   // wave-uniform
            gld16(src + off + lane * 4u, dst + off);
        }
    };
    issue(0u);

    const float L2E = 1.4426950408889634f;
    const float DOT_SCALE = 6.2000124e-06f;   // 1/(127*1270)
    float hold = 0.f;

    auto step = [&](unsigned s, const unsigned char* hRd, unsigned char* hWr,
                    const float* xc, float* pfc) {
        uint4 h0 = *(const uint4*)(hRd + off_q0);
        uint4 h1 = *(const uint4*)(hRd + off_q1);
        int acc[8] = {0, 0, 0, 0, 0, 0, 0, 0};
#pragma unroll
        for (int a = 0; a < 8; a++) {
            DOT4(acc[a], h0.x, w[a][0].x); DOT4(acc[a], h0.y, w[a][0].y);
            DOT4(acc[a], h0.z, w[a][0].z); DOT4(acc[a], h0.w, w[a][0].w);
            DOT4(acc[a], h1.x, w[a][1].x); DOT4(acc[a], h1.y, w[a][1].y);
            DOT4(acc[a], h1.z, w[a][1].z); DOT4(acc[a], h1.w, w[a][1].w);
        }
#pragma unroll
        for (int a = 0; a < 8; a++) acc[a] = bsum8(acc[a]);
        int ts = (jc & 2u) ? ((jc & 1u) ? acc[3] : acc[2])
                           : ((jc & 1u) ? acc[1] : acc[0]);
        int tg = (jc & 2u) ? ((jc & 1u) ? acc[7] : acc[6])
                           : ((jc & 1u) ? acc[5] : acc[4]);
        float sv = fmaf((float)ts, DOT_SCALE, xc[s * 512u + j]);
        float gv = fmaf((float)tg, DOT_SCALE, xc[s * 512u + 256u + j]);
        float gate = fast_rcp(1.f + fast_exp2(-gv * L2E));
        float prop = 1.f - 2.f * fast_rcp(1.f + fast_exp2(2.f * L2E * sv));
        float hnew = hold + gate * (prop - hold);
        if (ko < 4u) {
            pfc[s * 256u] = hold;                       // fire-and-forget
            int iv = (int)rintf(hnew * 127.f);
            hWr[j] = (unsigned char)((unsigned)iv & 0xFFu);
        }
        hold = hnew;
        if (s < 7u) STEP_BARRIER();
    };

    for (unsigned c = 0; c < 128u; ++c) {
        if (c == 0u) { asm volatile("s_waitcnt vmcnt(0) lgkmcnt(0)" ::: "memory"); }
        else         { asm volatile("s_waitcnt vmcnt(8) lgkmcnt(0)" ::: "memory"); }
        __builtin_amdgcn_s_barrier();
        asm volatile("" ::: "memory");
        if (c + 1u < 128u) issue(c + 1u);
        const float* xc = &xwC[c & 1u][0];
        float* pfc = pfb + c * 2048u;
#pragma unroll
        for (unsigned s = 0; s < 8u; ++s)
            step(s, (s & 1u) ? hbp1 : hbp0, (s & 1u) ? (unsigned char*)hbp0 : (unsigned char*)hbp1,
                 xc, pfc);
    }
}

// ---------------------------------------------------------------------------
// K5: router + delta mix at active tokens only. grid-stride over device count.
__launch_bounds__(256, 1)
__global__ void k_router(const unsigned* __restrict__ list, const float* __restrict__ accums_ro,
                         const float* __restrict__ prefix, const float* __restrict__ base,
                         const float* __restrict__ Wrh, const float* __restrict__ Wro,
                         const float* __restrict__ delta, float* __restrict__ out,
                         float* __restrict__ ent_sum) {
    const unsigned cnt = ((const unsigned*)accums_ro)[1];
    __shared__ float f[1280];
    __shared__ float hid[256];
    __shared__ float pr[16];
    const unsigned tid = threadIdx.x;
    for (unsigned idx = blockIdx.x; idx < cnt; idx += gridDim.x) {
        unsigned e = list[idx];
        unsigned tok = e >> 6, slot = e & 63u;
        f[tid] = prefix[(size_t)tok * 256u + tid];
#pragma unroll
        for (int q = 0; q < 4; q++)
            f[256u + q * 256u + tid] = base[(size_t)tok * 1024u + q * 256u + tid];
        __syncthreads();
        float a = 0.f;
        for (unsigned k = 0; k < 1280u; k++) a += f[k] * Wrh[k * 256u + tid];
        hid[tid] = tanhf(a);
        __syncthreads();
        if (tid < 16u) {
            float l = 0.f;
            for (unsigned k = 0; k < 256u; k++) l += hid[k] * Wro[k * 16u + tid];
            pr[tid] = l;
        }
        __syncthreads();
        if (tid == 0u) {
            float m = pr[0];
#pragma unroll
            for (int n = 1; n < 16; n++) m = fmaxf(m, pr[n]);
            float es[16]; float ssum = 0.f;
#pragma unroll
            for (int n = 0; n < 16; n++) { es[n] = expf(pr[n] - m); ssum += es[n]; }
            float inv = 1.f / ssum, ent = 0.f;
#pragma unroll
            for (int n = 0; n < 16; n++) {
                float p = es[n] * inv;
                pr[n] = p;
                ent -= p * logf(fmaxf(p, 1e-8f));
            }
            atomicAdd(ent_sum, ent);
        }
        __syncthreads();
        {
            const float* dslot = delta + (size_t)slot * 16u * 1024u;
            unsigned d0 = tid * 4u;
            float4 m4 = {0.f, 0.f, 0.f, 0.f};
#pragma unroll
            for (int n = 0; n < 16; n++) {
                float p = pr[n];
                float4 dv = *(const float4*)(dslot + n * 1024u + d0);
                m4.x += p * dv.x; m4.y += p * dv.y; m4.z += p * dv.z; m4.w += p * dv.w;
            }
            float* op = out + (size_t)tok * 1024u + d0;
            float4 cur = *(const float4*)op;
            cur.x += 0.25f * m4.x; cur.y += 0.25f * m4.y;
            cur.z += 0.25f * m4.z; cur.w += 0.25f * m4.w;
            *(float4*)op = cur;
        }
        __syncthreads();
    }
}

// ---------------------------------------------------------------------------
// K6: scalars
__global__ void k_final(const float* __restrict__ accums, float* __restrict__ out) {
    float ent = accums[0];
    unsigned cnt = ((const unsigned*)accums)[1];
    out[OUT_MAIN]     = (cnt > 0u) ? ent / (float)cnt : 0.f;
    out[OUT_MAIN + 1] = (float)cnt / 8192.f;
}

// ---------------------------------------------------------------------------
extern "C" void kernel_launch(void* const* d_in, const int* in_sizes, int n_in,
                              void* d_out, int out_size, void* d_ws, size_t ws_size,
                              hipStream_t stream) {
    const int*   ids  = (const int*)d_in[0];
    const float* base = (const float*)d_in[1];
    const int*   t2s  = (const int*)d_in[2];
    const float* Wsi  = (const float*)d_in[3];
    const float* Wsh  = (const float*)d_in[4];
    const float* Wgi  = (const float*)d_in[5];
    const float* Wgh  = (const float*)d_in[6];
    const float* Wrh  = (const float*)d_in[7];
    const float* Wro  = (const float*)d_in[8];
    const float* delta = (const float*)d_in[9];
    float* out = (float*)d_out;

    char* ws = (char*)d_ws;
    float*          XW     = (float*)(ws);                      // 16,777,216 B
    float*          prefix = (float*)(ws + 16777216);           //  8,388,608 B
    unsigned short* Bt     = (unsigned short*)(ws + 25165824);  //  1,048,576 B
    unsigned*       Wpack  = (unsigned*)(ws + 26214400);        //    131,072 B
    unsigned*       list   = (unsigned*)(ws + 26345472);        //     32,768 B
    float*          accums = (float*)(ws + 26378240);           //          8 B

    hipLaunchKernelGGL(k_copy_zero, dim3(2048), dim3(256), 0, stream,
                       (const float4*)base, (float4*)out, accums);
    hipLaunchKernelGGL(k_prep, dim3(2208), dim3(256), 0, stream,
                       Wsi, Wgi, Wsh, Wgh, ids, t2s, Bt, Wpack, list,
                       (unsigned*)accums + 1);
    hipLaunchKernelGGL(k_gemm, dim3(64, 2), dim3(512), 0, stream, base, Bt, XW);
    hipLaunchKernelGGL(k_rec, dim3(8), dim3(512), 0, stream, XW, Wpack, prefix);
    hipLaunchKernelGGL(k_router, dim3(64), dim3(256), 0, stream,
                       list, accums, prefix, base, Wrh, Wro, delta, out, accums);
    hipLaunchKernelGGL(k_final, dim3(1), dim3(1), 0, stream, accums, out);
}